// Round 10
// baseline (110.444 us; speedup 1.0000x reference)
//
#include <hip/hip_runtime.h>
#include <math.h>

#define B_ 32
#define T_ 1024
#define C_ 801
#define L_ 128
#define S_ 257            // 2*L+1
#define BLANK 800
#define NEGV -1e30f

#define CH 32             // chunk rows
#define NCH (T_ / CH)     // 32 chunks

typedef const float __attribute__((address_space(1))) f32_g;
typedef float __attribute__((address_space(3))) f32_l;

// -------- DPP helpers --------
template <int CTRL>
__device__ __forceinline__ float dppf(float v) {
    return __uint_as_float((unsigned)__builtin_amdgcn_update_dpp(
        0, (int)__float_as_uint(v), CTRL, 0xf, 0xf, true));
}
// lane l gets lane l-1's value; lane 0 gets 0.0f   [wave_shr:1]
__device__ __forceinline__ float shift_up1(float v) { return dppf<0x138>(v); }

// full-wave max of non-negative values, broadcast to all lanes via readlane(63)
__device__ __forceinline__ float wave_max_nn(float v) {
    v = fmaxf(v, dppf<0xB1>(v));    // xor1
    v = fmaxf(v, dppf<0x4E>(v));    // xor2
    v = fmaxf(v, dppf<0x141>(v));   // row_half_mirror (xor 4)
    v = fmaxf(v, dppf<0x140>(v));   // row_mirror      (xor 8)
    v = fmaxf(v, dppf<0x142>(v));   // row_bcast15
    v = fmaxf(v, dppf<0x143>(v));   // row_bcast31
    return __uint_as_float((unsigned)__builtin_amdgcn_readlane((int)__float_as_uint(v), 63));
}
// wave reductions valid in LANE 63 only
__device__ __forceinline__ float wave_red_max63(float v) {
    v = fmaxf(v, dppf<0xB1>(v));
    v = fmaxf(v, dppf<0x4E>(v));
    v = fmaxf(v, dppf<0x141>(v));
    v = fmaxf(v, dppf<0x140>(v));
    v = fmaxf(v, dppf<0x142>(v));
    v = fmaxf(v, dppf<0x143>(v));
    return v;
}
__device__ __forceinline__ float wave_red_sum63(float v) {
    v += dppf<0xB1>(v);
    v += dppf<0x4E>(v);
    v += dppf<0x141>(v);
    v += dppf<0x140>(v);
    v += dppf<0x142>(v);
    v += dppf<0x143>(v);
    return v;
}

// ================= Kernel A: fused LSE + staged linear-domain emissions =================
// ea[b][t][s] for s<256 (1024B rows), eq[b][t] = state 256.
__global__ __launch_bounds__(320) void stage_kernel(const float* __restrict__ logits,
                                                    const int* __restrict__ labels,
                                                    const int* __restrict__ lens,
                                                    float* __restrict__ ea,
                                                    float* __restrict__ eq) {
    const int t = blockIdx.x, b = blockIdx.y;
    const float* __restrict__ x = logits + ((size_t)b * T_ + t) * C_;
    __shared__ float xs[C_];
    __shared__ float wred[5];
    __shared__ float bval;
    const int tid = threadIdx.x, lane = tid & 63, wid = tid >> 6;

    float v0 = x[tid];
    float v1 = x[tid + 320];
    float v2 = (tid < 161) ? x[tid + 640] : NEGV;
    xs[tid] = v0;
    xs[tid + 320] = v1;
    if (tid < 161) xs[tid + 640] = v2;

    float m = fmaxf(v0, fmaxf(v1, v2));
    m = wave_red_max63(m);
    if (lane == 63) wred[wid] = m;
    __syncthreads();
    if (tid == 0)
        bval = fmaxf(fmaxf(wred[0], wred[1]), fmaxf(wred[2], fmaxf(wred[3], wred[4])));
    __syncthreads();
    const float gm = bval;

    float s = __expf(v0 - gm) + __expf(v1 - gm);
    if (tid < 161) s += __expf(v2 - gm);
    s = wave_red_sum63(s);
    __syncthreads();               // everyone has read gm
    if (lane == 63) wred[wid] = s;
    __syncthreads();
    if (tid == 0) bval = gm + __logf(wred[0] + wred[1] + wred[2] + wred[3] + wred[4]);
    __syncthreads();
    const float lse = bval;

    const int ll = lens[b];
    const int row = b * T_ + t;
    if (tid < 256) {
        float e = 0.f;
        if (tid < 2 * ll + 1) {
            int cls = (tid & 1) ? labels[b * L_ + (tid >> 1)] : BLANK;
            e = __expf(xs[cls] - lse);
        }
        ea[(size_t)row * 256 + tid] = e;
    } else if (tid == 256) {
        float e = (256 < 2 * ll + 1) ? __expf(xs[BLANK] - lse) : 0.f;
        eq[row] = e;
    }
}

// ================= Kernel B helpers =================

__device__ __forceinline__ void stage_chunk(const float* gbase, int c, float* lbase, int lane) {
    #pragma unroll
    for (int j = 0; j < CH; ++j) {
        const float* gp = gbase + ((size_t)(c * CH + j)) * 256 + 4 * lane;  // per-lane 16B
        float* lp = lbase + j * 256;                                        // wave-uniform base
        __builtin_amdgcn_global_load_lds((f32_g*)gp, (f32_l*)lp, 16, 0, 0);
    }
}

// LDS -> register chunk copy; fully unrolled, constant indices -> SROA to VGPRs.
__device__ __forceinline__ void load_regs(const float* bufp, int lane, float4 (&ev)[CH]) {
    #pragma unroll
    for (int j = 0; j < CH; ++j)
        ev[j] = *(const float4*)(bufp + j * 256 + 4 * lane);   // ds_read_b128
}

template <int J0>
__device__ __forceinline__ void compute_regs(const float4 (&ev)[CH], float eqc, int lane,
                                             float m21, float m23,
                                             float& p0, float& p1, float& p2, float& p3,
                                             float& q, int& E) {
    #pragma unroll
    for (int j = J0; j < CH; ++j) {
        float4 e = ev[j];
        float eqt = __uint_as_float(
            (unsigned)__builtin_amdgcn_readlane((int)__float_as_uint(eqc), j));
        float shp3 = shift_up1(p3);
        float n0 = (p0 + shp3) * e.x;
        float n1 = fmaf(m21, shp3, p1 + p0) * e.y;
        float n2 = (p2 + p1) * e.z;
        float n3 = fmaf(m23, p1, p3 + p2) * e.w;
        q = (q + p3) * eqt;
        p0 = n0; p1 = n1; p2 = n2; p3 = n3;
        if ((j & 7) == 7) {   // rescale every 8 steps (identical order/cadence to R9)
            float mx = fmaxf(fmaxf(p0, p1), fmaxf(p2, fmaxf(p3, q)));
            mx = wave_max_nn(mx);
            int e2_ = (int)((__float_as_uint(mx) >> 23) & 0xFF) - 126;
            float sc_ = __uint_as_float((unsigned)(127 - e2_) << 23);
            p0 *= sc_; p1 *= sc_; p2 *= sc_; p3 *= sc_; q *= sc_;
            E += e2_;
        }
    }
}

// ================= Kernel B: linear CTC forward, 1 wave/batch =================
// 3-stage pipeline: DMA(c+2)->LDS, ds_read(c+1)->regs, compute(c) from regs.
// ONLY fence: __syncthreads().
__global__ __launch_bounds__(64) void ctc_lds_kernel(const float* __restrict__ ea,
                                                     const float* __restrict__ eqg,
                                                     const int* __restrict__ labels,
                                                     const int* __restrict__ lens,
                                                     float* __restrict__ loss) {
    __shared__ float buf[2][CH * 256];   // 2 x 32 KB = 64 KB
    const int b = blockIdx.x;
    const int lane = threadIdx.x;
    const int ll = lens[b];
    const float* gbase = ea + (size_t)b * T_ * 256;
    const float* qbase = eqg + b * T_;

    // skip masks: only odd states (slots 1,3) are labels
    float m21 = 0.f, m23 = 0.f;
    {
        int s1 = 4 * lane + 1;
        if (s1 >= 3) {
            int li = s1 >> 1;   // 2*lane
            m21 = (labels[b * L_ + li] != labels[b * L_ + li - 1]) ? 1.f : 0.f;
        }
        int li3 = (4 * lane + 3) >> 1;  // 2*lane+1
        m23 = (labels[b * L_ + li3] != labels[b * L_ + li3 - 1]) ? 1.f : 0.f;
    }

    // prologue
    stage_chunk(gbase, 0, buf[0], lane);     // DMA chunk 0
    float eqC = qbase[lane & 31];            // chunk-0 eq rows
    __syncthreads();                         // chunk 0 in LDS

    float p0, p1, p2, p3, q;
    {
        float4 r0 = *(const float4*)(buf[0] + 4 * lane);
        p0 = (lane == 0) ? r0.x : 0.f;
        p1 = (lane == 0) ? r0.y : 0.f;
        p2 = 0.f; p3 = 0.f; q = 0.f;
    }
    int E = 0;

    float4 evA[CH], evB[CH];
    stage_chunk(gbase, 1, buf[1], lane);     // DMA chunk 1
    float eqN = qbase[CH + (lane & 31)];     // chunk-1 eq rows
    load_regs(buf[0], lane, evA);            // chunk 0 -> regs
    __syncthreads();                         // chunk 1 in LDS, evA ready

    #pragma unroll 1
    for (int c = 0; c < NCH; c += 2) {
        // even: compute chunk c (evA); ds_read c+1 -> evB; DMA c+2 -> buf0
        if (c + 2 < NCH) stage_chunk(gbase, c + 2, buf[0], lane);
        load_regs(buf[1], lane, evB);
        float eqHold = eqN;
        if (c + 2 < NCH) eqN = qbase[(c + 2) * CH + (lane & 31)];
        if (c == 0) compute_regs<1>(evA, eqC, lane, m21, m23, p0, p1, p2, p3, q, E);
        else        compute_regs<0>(evA, eqC, lane, m21, m23, p0, p1, p2, p3, q, E);
        eqC = eqHold;
        __syncthreads();

        // odd: compute chunk c+1 (evB); ds_read c+2 -> evA; DMA c+3 -> buf1
        if (c + 3 < NCH) stage_chunk(gbase, c + 3, buf[1], lane);
        if (c + 2 < NCH) load_regs(buf[0], lane, evA);
        float eqHold2 = eqN;
        if (c + 3 < NCH) eqN = qbase[(c + 3) * CH + (lane & 31)];
        compute_regs<0>(evB, eqC, lane, m21, m23, p0, p1, p2, p3, q, E);
        eqC = eqHold2;
        __syncthreads();
    }

    // termination: reuse buf[0] as the gather scratch
    *(float4*)(buf[0] + 4 * lane) = make_float4(p0, p1, p2, p3);
    if (lane == 63) buf[0][256] = q;
    __syncthreads();
    if (lane == 0) {
        float a1 = buf[0][2 * ll];
        float a2 = (ll > 0) ? buf[0][2 * ll - 1] : 0.f;
        loss[b] = -(__logf(a1 + a2) + (float)E * 0.69314718055994531f);
    }
}

__global__ void mean_kernel(const float* __restrict__ loss, float* __restrict__ out) {
    if (threadIdx.x == 0) {
        float s = 0.f;
        for (int i = 0; i < B_; ++i) s += loss[i];
        out[0] = s / (float)B_;
    }
}

// ================= FALLBACK PATH (small ws) =================

__global__ __launch_bounds__(256) void lse_kernel(const float* __restrict__ logits,
                                                  float* __restrict__ lse) {
    const int row = blockIdx.x;
    const float* __restrict__ x = logits + (size_t)row * C_;
    const int tid = threadIdx.x, lane = tid & 63, wid = tid >> 6;
    float v0 = x[tid], v1 = x[tid + 256], v2 = x[tid + 512];
    bool h3 = (tid + 768) < C_;
    float v3 = h3 ? x[tid + 768] : NEGV;
    float m = fmaxf(fmaxf(v0, v1), fmaxf(v2, v3));
    #pragma unroll
    for (int off = 32; off > 0; off >>= 1) m = fmaxf(m, __shfl_down(m, off));
    __shared__ float wred[4]; __shared__ float bm;
    if (lane == 0) wred[wid] = m;
    __syncthreads();
    if (tid == 0) bm = fmaxf(fmaxf(wred[0], wred[1]), fmaxf(wred[2], wred[3]));
    __syncthreads();
    m = bm;
    float s = __expf(v0 - m) + __expf(v1 - m) + __expf(v2 - m);
    if (h3) s += __expf(v3 - m);
    #pragma unroll
    for (int off = 32; off > 0; off >>= 1) s += __shfl_down(s, off);
    __syncthreads();
    if (lane == 0) wred[wid] = s;
    __syncthreads();
    if (tid == 0) lse[row] = m + __logf(wred[0] + wred[1] + wred[2] + wred[3]);
}

__global__ __launch_bounds__(320) void ctc_alpha_kernel(const float* __restrict__ logits,
                                                        const int* __restrict__ labels,
                                                        const int* __restrict__ lens,
                                                        const float* __restrict__ lse,
                                                        float* __restrict__ loss) {
    const int b = blockIdx.x;
    const int s = threadIdx.x;
    const int ll = lens[b];
    __shared__ float albuf[2][S_ + 2];
    if (s < 2) { albuf[0][s] = NEGV; albuf[1][s] = NEGV; }
    int cls = BLANK; bool allow2 = false;
    if (s < S_ && (s & 1)) {
        cls = labels[b * L_ + (s >> 1)];
        allow2 = (s >= 3) && (cls != labels[b * L_ + (s >> 1) - 1]);
    }
    const bool valid = (s < 2 * ll + 1);
    const float* __restrict__ xb = logits + (size_t)b * T_ * C_;
    const float* __restrict__ lseb = lse + b * T_;
    if (s < S_) {
        float e0 = xb[cls] - lseb[0];
        float a = (s == 0 || (s == 1 && ll > 0)) ? e0 : NEGV;
        if (!valid) a = NEGV;
        albuf[0][2 + s] = a;
    }
    __syncthreads();
    float e_next = xb[(size_t)C_ + cls];
    float lse_next = lseb[1];
    int cur = 0;
    for (int t = 1; t < T_; ++t) {
        const float e = e_next, lse_t = lse_next;
        if (t + 1 < T_) { e_next = xb[(size_t)(t + 1) * C_ + cls]; lse_next = lseb[t + 1]; }
        if (s < S_) {
            float a0 = albuf[cur][2 + s];
            float a1 = albuf[cur][1 + s];
            float a2 = allow2 ? albuf[cur][s] : NEGV;
            float m = fmaxf(fmaxf(a0, a1), a2);
            float r = m + __logf(__expf(a0 - m) + __expf(a1 - m) + __expf(a2 - m)) + (e - lse_t);
            if (!valid) r = NEGV;
            albuf[cur ^ 1][2 + s] = r;
        }
        __syncthreads();
        cur ^= 1;
    }
    if (s == 0) {
        float a1 = albuf[cur][2 + 2 * ll];
        float a2 = (ll > 0) ? albuf[cur][2 + 2 * ll - 1] : NEGV;
        float m = fmaxf(a1, a2);
        loss[b] = -(m + __logf(__expf(a1 - m) + __expf(a2 - m)));
    }
}

// ================= launch =================

extern "C" void kernel_launch(void* const* d_in, const int* in_sizes, int n_in,
                              void* d_out, int out_size, void* d_ws, size_t ws_size,
                              hipStream_t stream) {
    const float* logits = (const float*)d_in[0];
    const int*   labels = (const int*)d_in[1];
    const int*   lens   = (const int*)d_in[2];
    float* out = (float*)d_out;

    const size_t ea_elems = (size_t)B_ * T_ * 256;
    const size_t eq_elems = (size_t)B_ * T_;
    const size_t need = (ea_elems + eq_elems + B_) * sizeof(float);

    if (ws_size >= need) {
        float* ea   = (float*)d_ws;
        float* eq   = ea + ea_elems;
        float* loss = eq + eq_elems;
        dim3 grid(T_, B_);
        stage_kernel<<<grid, 320, 0, stream>>>(logits, labels, lens, ea, eq);
        ctc_lds_kernel<<<B_, 64, 0, stream>>>(ea, eq, labels, lens, loss);
        mean_kernel<<<1, 64, 0, stream>>>(loss, out);
    } else {
        float* lse  = (float*)d_ws;
        float* loss = lse + (size_t)B_ * T_;
        lse_kernel<<<B_ * T_, 256, 0, stream>>>(logits, lse);
        ctc_alpha_kernel<<<B_, 320, 0, stream>>>(logits, labels, lens, lse, loss);
        mean_kernel<<<1, 64, 0, stream>>>(loss, out);
    }
}

// Round 11
// 107.526 us; speedup vs baseline: 1.0271x; 1.0271x over previous
//
#include <hip/hip_runtime.h>
#include <math.h>

#define B_ 32
#define T_ 1024
#define C_ 801
#define L_ 128
#define S_ 257            // 2*L+1
#define BLANK 800
#define NEGV -1e30f

#define CH 32             // chunk rows
#define NCH (T_ / CH)     // 32 chunks
#define NW 8              // waves per block (1 compute + all stage)

typedef const float __attribute__((address_space(1))) f32_g;
typedef float __attribute__((address_space(3))) f32_l;

// -------- DPP helpers --------
template <int CTRL>
__device__ __forceinline__ float dppf(float v) {
    return __uint_as_float((unsigned)__builtin_amdgcn_update_dpp(
        0, (int)__float_as_uint(v), CTRL, 0xf, 0xf, true));
}
// lane l gets lane l-1's value; lane 0 gets 0.0f   [wave_shr:1]
__device__ __forceinline__ float shift_up1(float v) { return dppf<0x138>(v); }

// full-wave max of non-negative values, broadcast to all lanes via readlane(63)
__device__ __forceinline__ float wave_max_nn(float v) {
    v = fmaxf(v, dppf<0xB1>(v));    // xor1
    v = fmaxf(v, dppf<0x4E>(v));    // xor2
    v = fmaxf(v, dppf<0x141>(v));   // row_half_mirror (xor 4)
    v = fmaxf(v, dppf<0x140>(v));   // row_mirror      (xor 8)
    v = fmaxf(v, dppf<0x142>(v));   // row_bcast15
    v = fmaxf(v, dppf<0x143>(v));   // row_bcast31
    return __uint_as_float((unsigned)__builtin_amdgcn_readlane((int)__float_as_uint(v), 63));
}
// wave reductions valid in LANE 63 only
__device__ __forceinline__ float wave_red_max63(float v) {
    v = fmaxf(v, dppf<0xB1>(v));
    v = fmaxf(v, dppf<0x4E>(v));
    v = fmaxf(v, dppf<0x141>(v));
    v = fmaxf(v, dppf<0x140>(v));
    v = fmaxf(v, dppf<0x142>(v));
    v = fmaxf(v, dppf<0x143>(v));
    return v;
}
__device__ __forceinline__ float wave_red_sum63(float v) {
    v += dppf<0xB1>(v);
    v += dppf<0x4E>(v);
    v += dppf<0x141>(v);
    v += dppf<0x140>(v);
    v += dppf<0x142>(v);
    v += dppf<0x143>(v);
    return v;
}

// ================= Kernel A: fused LSE + staged linear-domain emissions =================
// ea[b][t][s] for s<256 (1024B rows), eq[b][t] = state 256.
__global__ __launch_bounds__(320) void stage_kernel(const float* __restrict__ logits,
                                                    const int* __restrict__ labels,
                                                    const int* __restrict__ lens,
                                                    float* __restrict__ ea,
                                                    float* __restrict__ eq) {
    const int t = blockIdx.x, b = blockIdx.y;
    const float* __restrict__ x = logits + ((size_t)b * T_ + t) * C_;
    __shared__ float xs[C_];
    __shared__ float wred[5];
    __shared__ float bval;
    const int tid = threadIdx.x, lane = tid & 63, wid = tid >> 6;

    float v0 = x[tid];
    float v1 = x[tid + 320];
    float v2 = (tid < 161) ? x[tid + 640] : NEGV;
    xs[tid] = v0;
    xs[tid + 320] = v1;
    if (tid < 161) xs[tid + 640] = v2;

    float m = fmaxf(v0, fmaxf(v1, v2));
    m = wave_red_max63(m);
    if (lane == 63) wred[wid] = m;
    __syncthreads();
    if (tid == 0)
        bval = fmaxf(fmaxf(wred[0], wred[1]), fmaxf(wred[2], fmaxf(wred[3], wred[4])));
    __syncthreads();
    const float gm = bval;

    float s = __expf(v0 - gm) + __expf(v1 - gm);
    if (tid < 161) s += __expf(v2 - gm);
    s = wave_red_sum63(s);
    __syncthreads();               // everyone has read gm
    if (lane == 63) wred[wid] = s;
    __syncthreads();
    if (tid == 0) bval = gm + __logf(wred[0] + wred[1] + wred[2] + wred[3] + wred[4]);
    __syncthreads();
    const float lse = bval;

    const int ll = lens[b];
    const int row = b * T_ + t;
    if (tid < 256) {
        float e = 0.f;
        if (tid < 2 * ll + 1) {
            int cls = (tid & 1) ? labels[b * L_ + (tid >> 1)] : BLANK;
            e = __expf(xs[cls] - lse);
        }
        ea[(size_t)row * 256 + tid] = e;
    } else if (tid == 256) {
        float e = (256 < 2 * ll + 1) ? __expf(xs[BLANK] - lse) : 0.f;
        eq[row] = e;
    }
}

// ================= Kernel B helpers =================

// Split the 32-row chunk DMA across NW waves: wave w stages rows {w, w+NW, ...}.
// Each wave owns its own vmcnt FIFO -> NW x outstanding-miss concurrency.
__device__ __forceinline__ void stage_chunk_split(const float* gbase, int c, float* lbase,
                                                  int lane, int wid) {
    #pragma unroll
    for (int k = 0; k < CH / NW; ++k) {
        int j = wid + k * NW;
        const float* gp = gbase + ((size_t)(c * CH + j)) * 256 + 4 * lane;  // per-lane 16B
        float* lp = lbase + j * 256;                                        // wave-uniform base
        __builtin_amdgcn_global_load_lds((f32_g*)gp, (f32_l*)lp, 16, 0, 0);
    }
}

template <int J0>
__device__ __forceinline__ void compute_chunk(const float* bufp, float eqc, int lane,
                                              float m21, float m23,
                                              float& p0, float& p1, float& p2, float& p3,
                                              float& q, int& E) {
    #pragma unroll
    for (int j = J0; j < CH; ++j) {
        float4 ev = *(const float4*)(bufp + j * 256 + 4 * lane);   // ds_read_b128
        float eqt = __uint_as_float(
            (unsigned)__builtin_amdgcn_readlane((int)__float_as_uint(eqc), j));
        float shp3 = shift_up1(p3);
        float n0 = (p0 + shp3) * ev.x;
        float n1 = fmaf(m21, shp3, p1 + p0) * ev.y;
        float n2 = (p2 + p1) * ev.z;
        float n3 = fmaf(m23, p1, p3 + p2) * ev.w;
        q = (q + p3) * eqt;
        p0 = n0; p1 = n1; p2 = n2; p3 = n3;
        if ((j & 7) == 7) {   // rescale every 8 steps (identical to R9)
            float mx = fmaxf(fmaxf(p0, p1), fmaxf(p2, fmaxf(p3, q)));
            mx = wave_max_nn(mx);
            int e2_ = (int)((__float_as_uint(mx) >> 23) & 0xFF) - 126;
            float sc_ = __uint_as_float((unsigned)(127 - e2_) << 23);
            p0 *= sc_; p1 *= sc_; p2 *= sc_; p3 *= sc_; q *= sc_;
            E += e2_;
        }
    }
}

// ================= Kernel B: linear CTC forward =================
// 8 waves: all waves co-issue the chunk DMA (miss-concurrency), wave 0 computes.
// ONLY fence: __syncthreads(). Numerics bit-identical to the R9 kernel.
__global__ __launch_bounds__(NW * 64) void ctc_lds_kernel(const float* __restrict__ ea,
                                                          const float* __restrict__ eqg,
                                                          const int* __restrict__ labels,
                                                          const int* __restrict__ lens,
                                                          float* __restrict__ loss) {
    __shared__ float buf[2][CH * 256];   // 2 x 32 KB = 64 KB
    const int b = blockIdx.x;
    const int tid = threadIdx.x;
    const int lane = tid & 63;
    const int wid = tid >> 6;
    const int ll = lens[b];
    const float* gbase = ea + (size_t)b * T_ * 256;
    const float* qbase = eqg + b * T_;

    // skip masks (wave 0 only uses them)
    float m21 = 0.f, m23 = 0.f;
    if (wid == 0) {
        int s1 = 4 * lane + 1;
        if (s1 >= 3) {
            int li = s1 >> 1;   // 2*lane
            m21 = (labels[b * L_ + li] != labels[b * L_ + li - 1]) ? 1.f : 0.f;
        }
        int li3 = (4 * lane + 3) >> 1;  // 2*lane+1
        m23 = (labels[b * L_ + li3] != labels[b * L_ + li3 - 1]) ? 1.f : 0.f;
    }

    // prologue: all waves stage chunk 0; barrier completes it
    stage_chunk_split(gbase, 0, buf[0], lane, wid);
    float eqC = 0.f, eqN = 0.f;
    if (wid == 0) eqC = qbase[lane & 31];
    __syncthreads();

    float p0 = 0.f, p1 = 0.f, p2 = 0.f, p3 = 0.f, q = 0.f;
    if (wid == 0) {
        float4 r0 = *(const float4*)(buf[0] + 4 * lane);
        p0 = (lane == 0) ? r0.x : 0.f;
        p1 = (lane == 0) ? r0.y : 0.f;
    }
    int E = 0;

    #pragma unroll 1
    for (int c = 0; c < NCH; ++c) {
        if (c + 1 < NCH) {
            stage_chunk_split(gbase, c + 1, buf[(c + 1) & 1], lane, wid);
            if (wid == 0) eqN = qbase[(c + 1) * CH + (lane & 31)];
        }
        if (wid == 0) {
            if (c == 0) compute_chunk<1>(buf[0],     eqC, lane, m21, m23, p0, p1, p2, p3, q, E);
            else        compute_chunk<0>(buf[c & 1], eqC, lane, m21, m23, p0, p1, p2, p3, q, E);
            eqC = eqN;
        }
        __syncthreads();
    }

    // termination: reuse buf[0] as the gather scratch
    if (wid == 0) {
        *(float4*)(buf[0] + 4 * lane) = make_float4(p0, p1, p2, p3);
        if (lane == 63) buf[0][256] = q;
    }
    __syncthreads();
    if (tid == 0) {
        float a1 = buf[0][2 * ll];
        float a2 = (ll > 0) ? buf[0][2 * ll - 1] : 0.f;
        loss[b] = -(__logf(a1 + a2) + (float)E * 0.69314718055994531f);
    }
}

__global__ void mean_kernel(const float* __restrict__ loss, float* __restrict__ out) {
    if (threadIdx.x == 0) {
        float s = 0.f;
        for (int i = 0; i < B_; ++i) s += loss[i];
        out[0] = s / (float)B_;
    }
}

// ================= FALLBACK PATH (small ws) =================

__global__ __launch_bounds__(256) void lse_kernel(const float* __restrict__ logits,
                                                  float* __restrict__ lse) {
    const int row = blockIdx.x;
    const float* __restrict__ x = logits + (size_t)row * C_;
    const int tid = threadIdx.x, lane = tid & 63, wid = tid >> 6;
    float v0 = x[tid], v1 = x[tid + 256], v2 = x[tid + 512];
    bool h3 = (tid + 768) < C_;
    float v3 = h3 ? x[tid + 768] : NEGV;
    float m = fmaxf(fmaxf(v0, v1), fmaxf(v2, v3));
    #pragma unroll
    for (int off = 32; off > 0; off >>= 1) m = fmaxf(m, __shfl_down(m, off));
    __shared__ float wred[4]; __shared__ float bm;
    if (lane == 0) wred[wid] = m;
    __syncthreads();
    if (tid == 0) bm = fmaxf(fmaxf(wred[0], wred[1]), fmaxf(wred[2], wred[3]));
    __syncthreads();
    m = bm;
    float s = __expf(v0 - m) + __expf(v1 - m) + __expf(v2 - m);
    if (h3) s += __expf(v3 - m);
    #pragma unroll
    for (int off = 32; off > 0; off >>= 1) s += __shfl_down(s, off);
    __syncthreads();
    if (lane == 0) wred[wid] = s;
    __syncthreads();
    if (tid == 0) lse[row] = m + __logf(wred[0] + wred[1] + wred[2] + wred[3]);
}

__global__ __launch_bounds__(320) void ctc_alpha_kernel(const float* __restrict__ logits,
                                                        const int* __restrict__ labels,
                                                        const int* __restrict__ lens,
                                                        const float* __restrict__ lse,
                                                        float* __restrict__ loss) {
    const int b = blockIdx.x;
    const int s = threadIdx.x;
    const int ll = lens[b];
    __shared__ float albuf[2][S_ + 2];
    if (s < 2) { albuf[0][s] = NEGV; albuf[1][s] = NEGV; }
    int cls = BLANK; bool allow2 = false;
    if (s < S_ && (s & 1)) {
        cls = labels[b * L_ + (s >> 1)];
        allow2 = (s >= 3) && (cls != labels[b * L_ + (s >> 1) - 1]);
    }
    const bool valid = (s < 2 * ll + 1);
    const float* __restrict__ xb = logits + (size_t)b * T_ * C_;
    const float* __restrict__ lseb = lse + b * T_;
    if (s < S_) {
        float e0 = xb[cls] - lseb[0];
        float a = (s == 0 || (s == 1 && ll > 0)) ? e0 : NEGV;
        if (!valid) a = NEGV;
        albuf[0][2 + s] = a;
    }
    __syncthreads();
    float e_next = xb[(size_t)C_ + cls];
    float lse_next = lseb[1];
    int cur = 0;
    for (int t = 1; t < T_; ++t) {
        const float e = e_next, lse_t = lse_next;
        if (t + 1 < T_) { e_next = xb[(size_t)(t + 1) * C_ + cls]; lse_next = lseb[t + 1]; }
        if (s < S_) {
            float a0 = albuf[cur][2 + s];
            float a1 = albuf[cur][1 + s];
            float a2 = allow2 ? albuf[cur][s] : NEGV;
            float m = fmaxf(fmaxf(a0, a1), a2);
            float r = m + __logf(__expf(a0 - m) + __expf(a1 - m) + __expf(a2 - m)) + (e - lse_t);
            if (!valid) r = NEGV;
            albuf[cur ^ 1][2 + s] = r;
        }
        __syncthreads();
        cur ^= 1;
    }
    if (s == 0) {
        float a1 = albuf[cur][2 + 2 * ll];
        float a2 = (ll > 0) ? albuf[cur][2 + 2 * ll - 1] : NEGV;
        float m = fmaxf(a1, a2);
        loss[b] = -(m + __logf(__expf(a1 - m) + __expf(a2 - m)));
    }
}

// ================= launch =================

extern "C" void kernel_launch(void* const* d_in, const int* in_sizes, int n_in,
                              void* d_out, int out_size, void* d_ws, size_t ws_size,
                              hipStream_t stream) {
    const float* logits = (const float*)d_in[0];
    const int*   labels = (const int*)d_in[1];
    const int*   lens   = (const int*)d_in[2];
    float* out = (float*)d_out;

    const size_t ea_elems = (size_t)B_ * T_ * 256;
    const size_t eq_elems = (size_t)B_ * T_;
    const size_t need = (ea_elems + eq_elems + B_) * sizeof(float);

    if (ws_size >= need) {
        float* ea   = (float*)d_ws;
        float* eq   = ea + ea_elems;
        float* loss = eq + eq_elems;
        dim3 grid(T_, B_);
        stage_kernel<<<grid, 320, 0, stream>>>(logits, labels, lens, ea, eq);
        ctc_lds_kernel<<<B_, NW * 64, 0, stream>>>(ea, eq, labels, lens, loss);
        mean_kernel<<<1, 64, 0, stream>>>(loss, out);
    } else {
        float* lse  = (float*)d_ws;
        float* loss = lse + (size_t)B_ * T_;
        lse_kernel<<<B_ * T_, 256, 0, stream>>>(logits, lse);
        ctc_alpha_kernel<<<B_, 320, 0, stream>>>(logits, labels, lens, lse, loss);
        mean_kernel<<<1, 64, 0, stream>>>(loss, out);
    }
}

// Round 12
// 98.559 us; speedup vs baseline: 1.1206x; 1.0910x over previous
//
#include <hip/hip_runtime.h>
#include <math.h>

#define B_ 32
#define T_ 1024
#define C_ 801
#define L_ 128
#define S_ 257            // 2*L+1
#define BLANK 800
#define NEGV -1e30f

#define CH 64             // chunk rows (bf16: 512B/row -> 32KB/chunk)
#define NCH (T_ / CH)     // 16 chunks
#define NW 8              // waves per block
#define LN2F 0.69314718055994531f

typedef const unsigned short __attribute__((address_space(1))) u16_g;
typedef unsigned short __attribute__((address_space(3))) u16_l;

// -------- DPP helpers --------
template <int CTRL>
__device__ __forceinline__ float dppf(float v) {
    return __uint_as_float((unsigned)__builtin_amdgcn_update_dpp(
        0, (int)__float_as_uint(v), CTRL, 0xf, 0xf, true));
}
// lane l gets lane l-1's value; lane 0 gets 0.0f   [wave_shr:1]
__device__ __forceinline__ float shift_up1(float v) { return dppf<0x138>(v); }

// full-wave max of non-negative values, broadcast to all lanes via readlane(63)
__device__ __forceinline__ float wave_max_nn(float v) {
    v = fmaxf(v, dppf<0xB1>(v));    // xor1
    v = fmaxf(v, dppf<0x4E>(v));    // xor2
    v = fmaxf(v, dppf<0x141>(v));   // row_half_mirror (xor 4)
    v = fmaxf(v, dppf<0x140>(v));   // row_mirror      (xor 8)
    v = fmaxf(v, dppf<0x142>(v));   // row_bcast15
    v = fmaxf(v, dppf<0x143>(v));   // row_bcast31
    return __uint_as_float((unsigned)__builtin_amdgcn_readlane((int)__float_as_uint(v), 63));
}
// wave reductions valid in LANE 63 only
__device__ __forceinline__ float wave_red_max63(float v) {
    v = fmaxf(v, dppf<0xB1>(v));
    v = fmaxf(v, dppf<0x4E>(v));
    v = fmaxf(v, dppf<0x141>(v));
    v = fmaxf(v, dppf<0x140>(v));
    v = fmaxf(v, dppf<0x142>(v));
    v = fmaxf(v, dppf<0x143>(v));
    return v;
}
__device__ __forceinline__ float wave_red_sum63(float v) {
    v += dppf<0xB1>(v);
    v += dppf<0x4E>(v);
    v += dppf<0x141>(v);
    v += dppf<0x140>(v);
    v += dppf<0x142>(v);
    v += dppf<0x143>(v);
    return v;
}

__device__ __forceinline__ float bf16_to_f32(unsigned short u) {
    return __uint_as_float((unsigned)u << 16);
}

// ================= Kernel A: fused LSE + staged bf16 emissions (pre-scaled by 2^10) =======
// ea[b][t][s] bf16 for s<256 (512B rows), eq[b][t] f32 = state 256.
__global__ __launch_bounds__(320) void stage_kernel(const float* __restrict__ logits,
                                                    const int* __restrict__ labels,
                                                    const int* __restrict__ lens,
                                                    unsigned short* __restrict__ ea,
                                                    float* __restrict__ eq) {
    const int t = blockIdx.x, b = blockIdx.y;
    const float* __restrict__ x = logits + ((size_t)b * T_ + t) * C_;
    __shared__ float xs[C_];
    __shared__ float wred[5];
    __shared__ float bval;
    const int tid = threadIdx.x, lane = tid & 63, wid = tid >> 6;

    float v0 = x[tid];
    float v1 = x[tid + 320];
    float v2 = (tid < 161) ? x[tid + 640] : NEGV;
    xs[tid] = v0;
    xs[tid + 320] = v1;
    if (tid < 161) xs[tid + 640] = v2;

    float m = fmaxf(v0, fmaxf(v1, v2));
    m = wave_red_max63(m);
    if (lane == 63) wred[wid] = m;
    __syncthreads();
    if (tid == 0)
        bval = fmaxf(fmaxf(wred[0], wred[1]), fmaxf(wred[2], fmaxf(wred[3], wred[4])));
    __syncthreads();
    const float gm = bval;

    float s = __expf(v0 - gm) + __expf(v1 - gm);
    if (tid < 161) s += __expf(v2 - gm);
    s = wave_red_sum63(s);
    __syncthreads();               // everyone has read gm
    if (lane == 63) wred[wid] = s;
    __syncthreads();
    if (tid == 0) bval = gm + __logf(wred[0] + wred[1] + wred[2] + wred[3] + wred[4]);
    __syncthreads();
    const float lse = bval;

    const int ll = lens[b];
    const int row = b * T_ + t;
    if (tid < 256) {
        float e = 0.f;
        if (tid < 2 * ll + 1) {
            int cls = (tid & 1) ? labels[b * L_ + (tid >> 1)] : BLANK;
            e = __expf(xs[cls] - lse) * 1024.0f;   // 2^10 pre-scale
        }
        unsigned u = __float_as_uint(e);
        u += 0x7FFF + ((u >> 16) & 1);             // round-to-nearest-even bf16
        ea[(size_t)row * 256 + tid] = (unsigned short)(u >> 16);
    } else if (tid == 256) {
        float e = (ll == 128) ? __expf(xs[BLANK] - lse) * 1024.0f : 0.f;
        eq[row] = e;
    }
}

// ================= Kernel B helpers =================

// 32 DMA instructions per chunk; each covers TWO 512B rows (1024B). Wave w takes i = w+8k.
__device__ __forceinline__ void stage_chunk_split(const unsigned short* gbase, int c,
                                                  unsigned short* lbase, int lane, int wid) {
    #pragma unroll
    for (int k = 0; k < 32 / NW; ++k) {
        int i = wid + k * NW;
        const unsigned short* gp = gbase + ((size_t)(c * CH + 2 * i)) * 256 + 8 * lane;
        unsigned short* lp = lbase + i * 512;      // wave-uniform dest
        __builtin_amdgcn_global_load_lds((u16_g*)gp, (u16_l*)lp, 16, 0, 0);
    }
}

template <int J0>
__device__ __forceinline__ void compute_chunk(const unsigned short* bufp, float eqc, int lane,
                                              float m21, float m23,
                                              float& p0, float& p1, float& p2, float& p3,
                                              float& q, int& E) {
    #pragma unroll
    for (int j = J0; j < CH; ++j) {
        ushort4 uv = *(const ushort4*)(bufp + j * 256 + 4 * lane);   // ds_read_b64
        float ex = bf16_to_f32(uv.x), ey = bf16_to_f32(uv.y);
        float ez = bf16_to_f32(uv.z), ew = bf16_to_f32(uv.w);
        float eqt = __uint_as_float(
            (unsigned)__builtin_amdgcn_readlane((int)__float_as_uint(eqc), j));
        float shp3 = shift_up1(p3);
        float n0 = (p0 + shp3) * ex;
        float n1 = fmaf(m21, shp3, p1 + p0) * ey;
        float n2 = (p2 + p1) * ez;
        float n3 = fmaf(m23, p1, p3 + p2) * ew;
        q = (q + p3) * eqt;
        p0 = n0; p1 = n1; p2 = n2; p3 = n3;
        if ((j & 7) == 7) {   // rescale every 8 steps; pre-scale keeps spread tight
            float mx = fmaxf(fmaxf(p0, p1), fmaxf(p2, fmaxf(p3, q)));
            mx = wave_max_nn(mx);
            int e2_ = (int)((__float_as_uint(mx) >> 23) & 0xFF) - 126;
            float sc_ = __uint_as_float((unsigned)(127 - e2_) << 23);
            p0 *= sc_; p1 *= sc_; p2 *= sc_; p3 *= sc_; q *= sc_;
            E += e2_;
        }
    }
}

// ================= Kernel B: linear CTC forward =================
// 8 waves co-issue the chunk DMA; wave 0 computes. ONLY fence: __syncthreads().
__global__ __launch_bounds__(NW * 64) void ctc_lds_kernel(const unsigned short* __restrict__ ea,
                                                          const float* __restrict__ eqg,
                                                          const int* __restrict__ labels,
                                                          const int* __restrict__ lens,
                                                          float* __restrict__ loss) {
    __shared__ unsigned short buf[2][CH * 256];   // 2 x 32 KB = 64 KB
    const int b = blockIdx.x;
    const int tid = threadIdx.x;
    const int lane = tid & 63;
    const int wid = tid >> 6;
    const int ll = lens[b];
    const unsigned short* gbase = ea + (size_t)b * T_ * 256;
    const float* qbase = eqg + b * T_;

    // skip masks (wave 0 only)
    float m21 = 0.f, m23 = 0.f;
    if (wid == 0) {
        int s1 = 4 * lane + 1;
        if (s1 >= 3) {
            int li = s1 >> 1;   // 2*lane
            m21 = (labels[b * L_ + li] != labels[b * L_ + li - 1]) ? 1.f : 0.f;
        }
        int li3 = (4 * lane + 3) >> 1;  // 2*lane+1
        m23 = (labels[b * L_ + li3] != labels[b * L_ + li3 - 1]) ? 1.f : 0.f;
    }

    // prologue: stage chunk 0
    stage_chunk_split(gbase, 0, buf[0], lane, wid);
    float eqC = 0.f, eqN = 0.f;
    if (wid == 0) eqC = qbase[lane];
    __syncthreads();

    float p0 = 0.f, p1 = 0.f, p2 = 0.f, p3 = 0.f, q = 0.f;
    if (wid == 0) {
        ushort4 r0 = *(const ushort4*)(&buf[0][4 * lane]);
        p0 = (lane == 0) ? bf16_to_f32(r0.x) : 0.f;
        p1 = (lane == 0) ? bf16_to_f32(r0.y) : 0.f;
    }
    int E = 0;

    #pragma unroll 1
    for (int c = 0; c < NCH; ++c) {
        if (c + 1 < NCH) {
            stage_chunk_split(gbase, c + 1, buf[(c + 1) & 1], lane, wid);
            if (wid == 0) eqN = qbase[(c + 1) * CH + lane];
        }
        if (wid == 0) {
            if (c == 0) compute_chunk<1>(buf[0],     eqC, lane, m21, m23, p0, p1, p2, p3, q, E);
            else        compute_chunk<0>(buf[c & 1], eqC, lane, m21, m23, p0, p1, p2, p3, q, E);
            eqC = eqN;
        }
        __syncthreads();
    }

    // termination: reuse buf as f32 gather scratch
    float* pf = (float*)(&buf[0][0]);
    if (wid == 0) {
        *(float4*)(pf + 4 * lane) = make_float4(p0, p1, p2, p3);
        if (lane == 63) pf[256] = q;
    }
    __syncthreads();
    if (tid == 0) {
        float a1 = pf[2 * ll];
        float a2 = (ll > 0) ? pf[2 * ll - 1] : 0.f;
        // emissions carried 2^10 each, 1024 of them -> subtract 10240*ln2
        loss[b] = -(__logf(a1 + a2) + ((float)E - 10240.0f) * LN2F);
    }
}

__global__ void mean_kernel(const float* __restrict__ loss, float* __restrict__ out) {
    if (threadIdx.x == 0) {
        float s = 0.f;
        for (int i = 0; i < B_; ++i) s += loss[i];
        out[0] = s / (float)B_;
    }
}

// ================= FALLBACK PATH (small ws) =================

__global__ __launch_bounds__(256) void lse_kernel(const float* __restrict__ logits,
                                                  float* __restrict__ lse) {
    const int row = blockIdx.x;
    const float* __restrict__ x = logits + (size_t)row * C_;
    const int tid = threadIdx.x, lane = tid & 63, wid = tid >> 6;
    float v0 = x[tid], v1 = x[tid + 256], v2 = x[tid + 512];
    bool h3 = (tid + 768) < C_;
    float v3 = h3 ? x[tid + 768] : NEGV;
    float m = fmaxf(fmaxf(v0, v1), fmaxf(v2, v3));
    #pragma unroll
    for (int off = 32; off > 0; off >>= 1) m = fmaxf(m, __shfl_down(m, off));
    __shared__ float wred[4]; __shared__ float bm;
    if (lane == 0) wred[wid] = m;
    __syncthreads();
    if (tid == 0) bm = fmaxf(fmaxf(wred[0], wred[1]), fmaxf(wred[2], wred[3]));
    __syncthreads();
    m = bm;
    float s = __expf(v0 - m) + __expf(v1 - m) + __expf(v2 - m);
    if (h3) s += __expf(v3 - m);
    #pragma unroll
    for (int off = 32; off > 0; off >>= 1) s += __shfl_down(s, off);
    __syncthreads();
    if (lane == 0) wred[wid] = s;
    __syncthreads();
    if (tid == 0) lse[row] = m + __logf(wred[0] + wred[1] + wred[2] + wred[3]);
}

__global__ __launch_bounds__(320) void ctc_alpha_kernel(const float* __restrict__ logits,
                                                        const int* __restrict__ labels,
                                                        const int* __restrict__ lens,
                                                        const float* __restrict__ lse,
                                                        float* __restrict__ loss) {
    const int b = blockIdx.x;
    const int s = threadIdx.x;
    const int ll = lens[b];
    __shared__ float albuf[2][S_ + 2];
    if (s < 2) { albuf[0][s] = NEGV; albuf[1][s] = NEGV; }
    int cls = BLANK; bool allow2 = false;
    if (s < S_ && (s & 1)) {
        cls = labels[b * L_ + (s >> 1)];
        allow2 = (s >= 3) && (cls != labels[b * L_ + (s >> 1) - 1]);
    }
    const bool valid = (s < 2 * ll + 1);
    const float* __restrict__ xb = logits + (size_t)b * T_ * C_;
    const float* __restrict__ lseb = lse + b * T_;
    if (s < S_) {
        float e0 = xb[cls] - lseb[0];
        float a = (s == 0 || (s == 1 && ll > 0)) ? e0 : NEGV;
        if (!valid) a = NEGV;
        albuf[0][2 + s] = a;
    }
    __syncthreads();
    float e_next = xb[(size_t)C_ + cls];
    float lse_next = lseb[1];
    int cur = 0;
    for (int t = 1; t < T_; ++t) {
        const float e = e_next, lse_t = lse_next;
        if (t + 1 < T_) { e_next = xb[(size_t)(t + 1) * C_ + cls]; lse_next = lseb[t + 1]; }
        if (s < S_) {
            float a0 = albuf[cur][2 + s];
            float a1 = albuf[cur][1 + s];
            float a2 = allow2 ? albuf[cur][s] : NEGV;
            float m = fmaxf(fmaxf(a0, a1), a2);
            float r = m + __logf(__expf(a0 - m) + __expf(a1 - m) + __expf(a2 - m)) + (e - lse_t);
            if (!valid) r = NEGV;
            albuf[cur ^ 1][2 + s] = r;
        }
        __syncthreads();
        cur ^= 1;
    }
    if (s == 0) {
        float a1 = albuf[cur][2 + 2 * ll];
        float a2 = (ll > 0) ? albuf[cur][2 + 2 * ll - 1] : NEGV;
        float m = fmaxf(a1, a2);
        loss[b] = -(m + __logf(__expf(a1 - m) + __expf(a2 - m)));
    }
}

// ================= launch =================

extern "C" void kernel_launch(void* const* d_in, const int* in_sizes, int n_in,
                              void* d_out, int out_size, void* d_ws, size_t ws_size,
                              hipStream_t stream) {
    const float* logits = (const float*)d_in[0];
    const int*   labels = (const int*)d_in[1];
    const int*   lens   = (const int*)d_in[2];
    float* out = (float*)d_out;

    const size_t ea_elems = (size_t)B_ * T_ * 256;           // ushorts
    const size_t eq_elems = (size_t)B_ * T_;                 // floats
    const size_t need = ea_elems * 2 + (eq_elems + B_) * 4;

    if (ws_size >= need) {
        unsigned short* ea = (unsigned short*)d_ws;
        float* eq   = (float*)(ea + ea_elems);
        float* loss = eq + eq_elems;
        dim3 grid(T_, B_);
        stage_kernel<<<grid, 320, 0, stream>>>(logits, labels, lens, ea, eq);
        ctc_lds_kernel<<<B_, NW * 64, 0, stream>>>(ea, eq, labels, lens, loss);
        mean_kernel<<<1, 64, 0, stream>>>(loss, out);
    } else {
        float* lse  = (float*)d_ws;
        float* loss = lse + (size_t)B_ * T_;
        lse_kernel<<<B_ * T_, 256, 0, stream>>>(logits, lse);
        ctc_alpha_kernel<<<B_, 320, 0, stream>>>(logits, labels, lens, lse, loss);
        mean_kernel<<<1, 64, 0, stream>>>(loss, out);
    }
}

// Round 13
// 79.085 us; speedup vs baseline: 1.3965x; 1.2462x over previous
//
#include <hip/hip_runtime.h>
#include <math.h>

#define B_ 32
#define T_ 1024
#define C_ 801
#define L_ 128
#define S_ 257            // 2*L+1
#define BLANK 800
#define NEGV -1e30f

#define CH 64             // chunk rows (bf16: 512B/row -> 32KB/chunk)
#define NCH (T_ / CH)     // 16 chunks
#define NW 8              // waves per block (ctc kernel)
#define LN2F 0.69314718055994531f

typedef const unsigned short __attribute__((address_space(1))) u16_g;
typedef unsigned short __attribute__((address_space(3))) u16_l;

// -------- DPP helpers --------
template <int CTRL>
__device__ __forceinline__ float dppf(float v) {
    return __uint_as_float((unsigned)__builtin_amdgcn_update_dpp(
        0, (int)__float_as_uint(v), CTRL, 0xf, 0xf, true));
}
// lane l gets lane l-1's value; lane 0 gets 0.0f   [wave_shr:1]
__device__ __forceinline__ float shift_up1(float v) { return dppf<0x138>(v); }

// butterfly reduce; result valid in LANE 63 for ANY input values
// (bound_ctrl zeros only land in lanes that lane-63's dataflow never reads)
__device__ __forceinline__ float wave_red_max63(float v) {
    v = fmaxf(v, dppf<0xB1>(v));    // xor1
    v = fmaxf(v, dppf<0x4E>(v));    // xor2
    v = fmaxf(v, dppf<0x141>(v));   // row_half_mirror (xor4)
    v = fmaxf(v, dppf<0x140>(v));   // row_mirror      (xor8)
    v = fmaxf(v, dppf<0x142>(v));   // row_bcast15
    v = fmaxf(v, dppf<0x143>(v));   // row_bcast31
    return v;
}
__device__ __forceinline__ float wave_red_sum63(float v) {
    v += dppf<0xB1>(v);
    v += dppf<0x4E>(v);
    v += dppf<0x141>(v);
    v += dppf<0x140>(v);
    v += dppf<0x142>(v);
    v += dppf<0x143>(v);
    return v;
}
__device__ __forceinline__ float bcast63(float v) {
    return __uint_as_float((unsigned)__builtin_amdgcn_readlane((int)__float_as_uint(v), 63));
}
// full-wave max broadcast (nonneg OK for rescale use)
__device__ __forceinline__ float wave_max_nn(float v) { return bcast63(wave_red_max63(v)); }

__device__ __forceinline__ float bf16_to_f32(unsigned short u) {
    return __uint_as_float((unsigned)u << 16);
}
__device__ __forceinline__ unsigned short f32_to_bf16_rne(float f) {
    unsigned u = __float_as_uint(f);
    u += 0x7FFF + ((u >> 16) & 1);
    return (unsigned short)(u >> 16);
}

// ================= Kernel A: barrier-free fused LSE + bf16 emission staging ==============
// One WAVE per (b,t) row; 4 independent waves per block; zero __syncthreads.
// ea[b][t][s] bf16 (512B rows, pre-scaled 2^10), eq[b][t] f32 = state 256 (pre-scaled).
__global__ __launch_bounds__(256) void stage_kernel(const float* __restrict__ logits,
                                                    const int* __restrict__ labels,
                                                    const int* __restrict__ lens,
                                                    unsigned short* __restrict__ ea,
                                                    float* __restrict__ eq) {
    const int wv   = threadIdx.x >> 6;
    const int lane = threadIdx.x & 63;
    const int b = blockIdx.y;
    const int t = blockIdx.x * 4 + wv;
    const int row = b * T_ + t;
    const float* __restrict__ x = logits + (size_t)row * C_;

    __shared__ float xs4[4][816];
    float* xs = xs4[wv];

    // 13 predicated loads/lane (801 = 12*64 + 33)
    float v[13];
    #pragma unroll
    for (int k = 0; k < 12; ++k) v[k] = x[lane + 64 * k];
    v[12] = (lane < 33) ? x[768 + lane] : NEGV;

    // wave LSE (no barriers)
    float m = v[0];
    #pragma unroll
    for (int k = 1; k < 13; ++k) m = fmaxf(m, v[k]);
    m = bcast63(wave_red_max63(m));

    float s = 0.f;
    #pragma unroll
    for (int k = 0; k < 13; ++k) s += __expf(v[k] - m);   // masked lane adds exp(NEGV)=0
    s = bcast63(wave_red_sum63(s));
    const float lse = m + __logf(s);

    // stage row into this wave's LDS slice (same-wave ordering via lgkmcnt)
    #pragma unroll
    for (int k = 0; k < 12; ++k) xs[lane + 64 * k] = v[k];
    if (lane < 33) xs[768 + lane] = v[12];

    // outputs: lane owns states 4*lane .. 4*lane+3
    const int ll = lens[b];
    const int smax = 2 * ll + 1;
    const float ebl = __expf(xs[BLANK] - lse) * 1024.0f;   // blank emission (pre-scaled)
    const int cls1 = labels[b * L_ + 2 * lane];
    const int cls3 = labels[b * L_ + 2 * lane + 1];
    const int s0 = 4 * lane;
    float e0 = (s0     < smax) ? ebl : 0.f;
    float e1 = (s0 + 1 < smax) ? __expf(xs[cls1] - lse) * 1024.0f : 0.f;
    float e2 = (s0 + 2 < smax) ? ebl : 0.f;
    float e3 = (s0 + 3 < smax) ? __expf(xs[cls3] - lse) * 1024.0f : 0.f;

    ushort4 o;
    o.x = f32_to_bf16_rne(e0);
    o.y = f32_to_bf16_rne(e1);
    o.z = f32_to_bf16_rne(e2);
    o.w = f32_to_bf16_rne(e3);
    *(ushort4*)(ea + (size_t)row * 256 + 4 * lane) = o;

    if (lane == 0) eq[row] = (ll == 128) ? ebl : 0.f;      // state 256
}

// ================= Kernel B helpers =================

// 32 DMA instructions per chunk; each covers TWO 512B rows (1024B). Wave w takes i = w+8k.
__device__ __forceinline__ void stage_chunk_split(const unsigned short* gbase, int c,
                                                  unsigned short* lbase, int lane, int wid) {
    #pragma unroll
    for (int k = 0; k < 32 / NW; ++k) {
        int i = wid + k * NW;
        const unsigned short* gp = gbase + ((size_t)(c * CH + 2 * i)) * 256 + 8 * lane;
        unsigned short* lp = lbase + i * 512;      // wave-uniform dest
        __builtin_amdgcn_global_load_lds((u16_g*)gp, (u16_l*)lp, 16, 0, 0);
    }
}

template <int J0>
__device__ __forceinline__ void compute_chunk(const unsigned short* bufp, float eqc, int lane,
                                              float m21, float m23,
                                              float& p0, float& p1, float& p2, float& p3,
                                              float& q, int& E) {
    #pragma unroll
    for (int j = J0; j < CH; ++j) {
        ushort4 uv = *(const ushort4*)(bufp + j * 256 + 4 * lane);   // ds_read_b64
        float ex = bf16_to_f32(uv.x), ey = bf16_to_f32(uv.y);
        float ez = bf16_to_f32(uv.z), ew = bf16_to_f32(uv.w);
        float eqt = __uint_as_float(
            (unsigned)__builtin_amdgcn_readlane((int)__float_as_uint(eqc), j));
        float shp3 = shift_up1(p3);
        float n0 = (p0 + shp3) * ex;
        float n1 = fmaf(m21, shp3, p1 + p0) * ey;
        float n2 = (p2 + p1) * ez;
        float n3 = fmaf(m23, p1, p3 + p2) * ew;
        q = (q + p3) * eqt;
        p0 = n0; p1 = n1; p2 = n2; p3 = n3;
        if ((j & 7) == 7) {   // rescale every 8 steps
            float mx = fmaxf(fmaxf(p0, p1), fmaxf(p2, fmaxf(p3, q)));
            mx = wave_max_nn(mx);
            int e2_ = (int)((__float_as_uint(mx) >> 23) & 0xFF) - 126;
            float sc_ = __uint_as_float((unsigned)(127 - e2_) << 23);
            p0 *= sc_; p1 *= sc_; p2 *= sc_; p3 *= sc_; q *= sc_;
            E += e2_;
        }
    }
}

// ================= Kernel B: linear CTC forward =================
// 8 waves co-issue the chunk DMA; wave 0 computes. ONLY fence: __syncthreads().
__global__ __launch_bounds__(NW * 64) void ctc_lds_kernel(const unsigned short* __restrict__ ea,
                                                          const float* __restrict__ eqg,
                                                          const int* __restrict__ labels,
                                                          const int* __restrict__ lens,
                                                          float* __restrict__ loss) {
    __shared__ unsigned short buf[2][CH * 256];   // 2 x 32 KB = 64 KB
    const int b = blockIdx.x;
    const int tid = threadIdx.x;
    const int lane = tid & 63;
    const int wid = tid >> 6;
    const int ll = lens[b];
    const unsigned short* gbase = ea + (size_t)b * T_ * 256;
    const float* qbase = eqg + b * T_;

    // skip masks (wave 0 only)
    float m21 = 0.f, m23 = 0.f;
    if (wid == 0) {
        int s1 = 4 * lane + 1;
        if (s1 >= 3) {
            int li = s1 >> 1;   // 2*lane
            m21 = (labels[b * L_ + li] != labels[b * L_ + li - 1]) ? 1.f : 0.f;
        }
        int li3 = (4 * lane + 3) >> 1;  // 2*lane+1
        m23 = (labels[b * L_ + li3] != labels[b * L_ + li3 - 1]) ? 1.f : 0.f;
    }

    // prologue: stage chunk 0
    stage_chunk_split(gbase, 0, buf[0], lane, wid);
    float eqC = 0.f, eqN = 0.f;
    if (wid == 0) eqC = qbase[lane];
    __syncthreads();

    float p0 = 0.f, p1 = 0.f, p2 = 0.f, p3 = 0.f, q = 0.f;
    if (wid == 0) {
        ushort4 r0 = *(const ushort4*)(&buf[0][4 * lane]);
        p0 = (lane == 0) ? bf16_to_f32(r0.x) : 0.f;
        p1 = (lane == 0) ? bf16_to_f32(r0.y) : 0.f;
    }
    int E = 0;

    #pragma unroll 1
    for (int c = 0; c < NCH; ++c) {
        if (c + 1 < NCH) {
            stage_chunk_split(gbase, c + 1, buf[(c + 1) & 1], lane, wid);
            if (wid == 0) eqN = qbase[(c + 1) * CH + lane];
        }
        if (wid == 0) {
            if (c == 0) compute_chunk<1>(buf[0],     eqC, lane, m21, m23, p0, p1, p2, p3, q, E);
            else        compute_chunk<0>(buf[c & 1], eqC, lane, m21, m23, p0, p1, p2, p3, q, E);
            eqC = eqN;
        }
        __syncthreads();
    }

    // termination: reuse buf as f32 gather scratch
    float* pf = (float*)(&buf[0][0]);
    if (wid == 0) {
        *(float4*)(pf + 4 * lane) = make_float4(p0, p1, p2, p3);
        if (lane == 63) pf[256] = q;
    }
    __syncthreads();
    if (tid == 0) {
        float a1 = pf[2 * ll];
        float a2 = (ll > 0) ? pf[2 * ll - 1] : 0.f;
        // emissions carried 2^10 each, 1024 of them -> subtract 10240*ln2
        loss[b] = -(__logf(a1 + a2) + ((float)E - 10240.0f) * LN2F);
    }
}

__global__ void mean_kernel(const float* __restrict__ loss, float* __restrict__ out) {
    if (threadIdx.x == 0) {
        float s = 0.f;
        for (int i = 0; i < B_; ++i) s += loss[i];
        out[0] = s / (float)B_;
    }
}

// ================= FALLBACK PATH (small ws) =================

__global__ __launch_bounds__(256) void lse_kernel(const float* __restrict__ logits,
                                                  float* __restrict__ lse) {
    const int row = blockIdx.x;
    const float* __restrict__ x = logits + (size_t)row * C_;
    const int tid = threadIdx.x, lane = tid & 63, wid = tid >> 6;
    float v0 = x[tid], v1 = x[tid + 256], v2 = x[tid + 512];
    bool h3 = (tid + 768) < C_;
    float v3 = h3 ? x[tid + 768] : NEGV;
    float m = fmaxf(fmaxf(v0, v1), fmaxf(v2, v3));
    #pragma unroll
    for (int off = 32; off > 0; off >>= 1) m = fmaxf(m, __shfl_down(m, off));
    __shared__ float wred[4]; __shared__ float bm;
    if (lane == 0) wred[wid] = m;
    __syncthreads();
    if (tid == 0) bm = fmaxf(fmaxf(wred[0], wred[1]), fmaxf(wred[2], wred[3]));
    __syncthreads();
    m = bm;
    float s = __expf(v0 - m) + __expf(v1 - m) + __expf(v2 - m);
    if (h3) s += __expf(v3 - m);
    #pragma unroll
    for (int off = 32; off > 0; off >>= 1) s += __shfl_down(s, off);
    __syncthreads();
    if (lane == 0) wred[wid] = s;
    __syncthreads();
    if (tid == 0) lse[row] = m + __logf(wred[0] + wred[1] + wred[2] + wred[3]);
}

__global__ __launch_bounds__(320) void ctc_alpha_kernel(const float* __restrict__ logits,
                                                        const int* __restrict__ labels,
                                                        const int* __restrict__ lens,
                                                        const float* __restrict__ lse,
                                                        float* __restrict__ loss) {
    const int b = blockIdx.x;
    const int s = threadIdx.x;
    const int ll = lens[b];
    __shared__ float albuf[2][S_ + 2];
    if (s < 2) { albuf[0][s] = NEGV; albuf[1][s] = NEGV; }
    int cls = BLANK; bool allow2 = false;
    if (s < S_ && (s & 1)) {
        cls = labels[b * L_ + (s >> 1)];
        allow2 = (s >= 3) && (cls != labels[b * L_ + (s >> 1) - 1]);
    }
    const bool valid = (s < 2 * ll + 1);
    const float* __restrict__ xb = logits + (size_t)b * T_ * C_;
    const float* __restrict__ lseb = lse + b * T_;
    if (s < S_) {
        float e0 = xb[cls] - lseb[0];
        float a = (s == 0 || (s == 1 && ll > 0)) ? e0 : NEGV;
        if (!valid) a = NEGV;
        albuf[0][2 + s] = a;
    }
    __syncthreads();
    float e_next = xb[(size_t)C_ + cls];
    float lse_next = lseb[1];
    int cur = 0;
    for (int t = 1; t < T_; ++t) {
        const float e = e_next, lse_t = lse_next;
        if (t + 1 < T_) { e_next = xb[(size_t)(t + 1) * C_ + cls]; lse_next = lseb[t + 1]; }
        if (s < S_) {
            float a0 = albuf[cur][2 + s];
            float a1 = albuf[cur][1 + s];
            float a2 = allow2 ? albuf[cur][s] : NEGV;
            float m = fmaxf(fmaxf(a0, a1), a2);
            float r = m + __logf(__expf(a0 - m) + __expf(a1 - m) + __expf(a2 - m)) + (e - lse_t);
            if (!valid) r = NEGV;
            albuf[cur ^ 1][2 + s] = r;
        }
        __syncthreads();
        cur ^= 1;
    }
    if (s == 0) {
        float a1 = albuf[cur][2 + 2 * ll];
        float a2 = (ll > 0) ? albuf[cur][2 + 2 * ll - 1] : NEGV;
        float m = fmaxf(a1, a2);
        loss[b] = -(m + __logf(__expf(a1 - m) + __expf(a2 - m)));
    }
}

// ================= launch =================

extern "C" void kernel_launch(void* const* d_in, const int* in_sizes, int n_in,
                              void* d_out, int out_size, void* d_ws, size_t ws_size,
                              hipStream_t stream) {
    const float* logits = (const float*)d_in[0];
    const int*   labels = (const int*)d_in[1];
    const int*   lens   = (const int*)d_in[2];
    float* out = (float*)d_out;

    const size_t ea_elems = (size_t)B_ * T_ * 256;           // ushorts
    const size_t eq_elems = (size_t)B_ * T_;                 // floats
    const size_t need = ea_elems * 2 + (eq_elems + B_) * 4;

    if (ws_size >= need) {
        unsigned short* ea = (unsigned short*)d_ws;
        float* eq   = (float*)(ea + ea_elems);
        float* loss = eq + eq_elems;
        dim3 grid(T_ / 4, B_);
        stage_kernel<<<grid, 256, 0, stream>>>(logits, labels, lens, ea, eq);
        ctc_lds_kernel<<<B_, NW * 64, 0, stream>>>(ea, eq, labels, lens, loss);
        mean_kernel<<<1, 64, 0, stream>>>(loss, out);
    } else {
        float* lse  = (float*)d_ws;
        float* loss = lse + (size_t)B_ * T_;
        lse_kernel<<<B_ * T_, 256, 0, stream>>>(logits, lse);
        ctc_alpha_kernel<<<B_, 320, 0, stream>>>(logits, labels, lens, lse, loss);
        mean_kernel<<<1, 64, 0, stream>>>(loss, out);
    }
}

// Round 14
// 78.669 us; speedup vs baseline: 1.4039x; 1.0053x over previous
//
#include <hip/hip_runtime.h>
#include <math.h>

#define B_ 32
#define T_ 1024
#define C_ 801
#define L_ 128
#define S_ 257            // 2*L+1
#define BLANK 800
#define NEGV -1e30f

#define CH 64             // chunk rows (bf16: 512B/row -> 32KB/chunk)
#define NCH (T_ / CH)     // 16 chunks
#define NW 8              // waves per block (ctc kernel)
#define LN2F 0.69314718055994531f

typedef const unsigned short __attribute__((address_space(1))) u16_g;
typedef unsigned short __attribute__((address_space(3))) u16_l;

// -------- DPP helpers --------
template <int CTRL>
__device__ __forceinline__ float dppf(float v) {
    return __uint_as_float((unsigned)__builtin_amdgcn_update_dpp(
        0, (int)__float_as_uint(v), CTRL, 0xf, 0xf, true));
}
// lane l gets lane l-1's value; lane 0 gets 0.0f   [wave_shr:1]
__device__ __forceinline__ float shift_up1(float v) { return dppf<0x138>(v); }

// butterfly reduce; result valid in LANE 63 for ANY input values
__device__ __forceinline__ float wave_red_max63(float v) {
    v = fmaxf(v, dppf<0xB1>(v));    // xor1
    v = fmaxf(v, dppf<0x4E>(v));    // xor2
    v = fmaxf(v, dppf<0x141>(v));   // row_half_mirror (xor4)
    v = fmaxf(v, dppf<0x140>(v));   // row_mirror      (xor8)
    v = fmaxf(v, dppf<0x142>(v));   // row_bcast15
    v = fmaxf(v, dppf<0x143>(v));   // row_bcast31
    return v;
}
__device__ __forceinline__ float wave_red_sum63(float v) {
    v += dppf<0xB1>(v);
    v += dppf<0x4E>(v);
    v += dppf<0x141>(v);
    v += dppf<0x140>(v);
    v += dppf<0x142>(v);
    v += dppf<0x143>(v);
    return v;
}
__device__ __forceinline__ float bcast63(float v) {
    return __uint_as_float((unsigned)__builtin_amdgcn_readlane((int)__float_as_uint(v), 63));
}
__device__ __forceinline__ float wave_max_nn(float v) { return bcast63(wave_red_max63(v)); }

__device__ __forceinline__ float bf16_to_f32(unsigned short u) {
    return __uint_as_float((unsigned)u << 16);
}
__device__ __forceinline__ float bf16lo(unsigned u) { return __uint_as_float(u << 16); }
__device__ __forceinline__ float bf16hi(unsigned u) { return __uint_as_float(u & 0xFFFF0000u); }
__device__ __forceinline__ unsigned short f32_to_bf16_rne(float f) {
    unsigned u = __float_as_uint(f);
    u += 0x7FFF + ((u >> 16) & 1);
    return (unsigned short)(u >> 16);
}

// ================= Kernel A: vectorized fused LSE + bf16 emission staging ==============
// Block = 4 rows (12816 B, float4-aligned). Cooperative float4 load -> LDS, one barrier,
// then wave wv owns row wv: DPP-reduce LSE, emit bf16 (pre-scaled 2^10) into the
// PAIR-INTERLEAVED layout: pair p, lane l holds rows (2p,2p+1) states 4l..4l+3 in 16B.
__global__ __launch_bounds__(256) void stage_kernel(const float* __restrict__ logits,
                                                    const int* __restrict__ labels,
                                                    const int* __restrict__ lens,
                                                    unsigned short* __restrict__ ea,
                                                    float* __restrict__ eq) {
    const int tid = threadIdx.x, lane = tid & 63, wv = tid >> 6;
    const int b = blockIdx.y;
    const int t0 = blockIdx.x * 4;
    const float* __restrict__ base = logits + ((size_t)b * T_ + t0) * C_;  // 16B-aligned
    __shared__ float xs[4 * C_];   // 12816 B

    const float4* src = (const float4*)base;
    #pragma unroll
    for (int k = 0; k < 4; ++k) {
        int idx = tid + 256 * k;
        if (idx < 801) ((float4*)xs)[idx] = src[idx];
    }
    __syncthreads();

    const float* xr = xs + wv * C_;
    // wave LSE (values kept in regs for the exp pass)
    float v[13];
    float m = NEGV;
    #pragma unroll
    for (int k = 0; k < 12; ++k) { v[k] = xr[lane + 64 * k]; m = fmaxf(m, v[k]); }
    v[12] = (lane < 33) ? xr[768 + lane] : NEGV;
    m = fmaxf(m, v[12]);
    m = bcast63(wave_red_max63(m));

    float s = 0.f;
    #pragma unroll
    for (int k = 0; k < 13; ++k) s += __expf(v[k] - m);
    s = bcast63(wave_red_sum63(s));
    const float lse = m + __logf(s);

    const int ll = lens[b];
    const int t = t0 + wv;
    const int row = b * T_ + t;
    const int smax = 2 * ll + 1;
    const float ebl = __expf(xr[BLANK] - lse) * 1024.0f;
    const int cls1 = labels[b * L_ + 2 * lane];
    const int cls3 = labels[b * L_ + 2 * lane + 1];
    const int s0 = 4 * lane;
    float e0 = (s0     < smax) ? ebl : 0.f;
    float e1 = (s0 + 1 < smax) ? __expf(xr[cls1] - lse) * 1024.0f : 0.f;
    float e2 = (s0 + 2 < smax) ? ebl : 0.f;
    float e3 = (s0 + 3 < smax) ? __expf(xr[cls3] - lse) * 1024.0f : 0.f;

    ushort4 o;
    o.x = f32_to_bf16_rne(e0);
    o.y = f32_to_bf16_rne(e1);
    o.z = f32_to_bf16_rne(e2);
    o.w = f32_to_bf16_rne(e3);
    // pair-interleaved: pair stride 512 ushorts (1KB), lane stride 8 ushorts, parity 4
    *(ushort4*)(ea + ((size_t)(row >> 1)) * 512 + 8 * lane + (row & 1) * 4) = o;

    if (lane == 0) eq[row] = (ll == 128) ? ebl : 0.f;      // state 256
}

// ================= Kernel B helpers =================

// 32 DMA instructions per chunk; each covers one 1KB row-pair. Wave w takes i = w+8k.
__device__ __forceinline__ void stage_chunk_split(const unsigned short* gbase, int c,
                                                  unsigned short* lbase, int lane, int wid) {
    #pragma unroll
    for (int k = 0; k < 32 / NW; ++k) {
        int i = wid + k * NW;
        const unsigned short* gp = gbase + ((size_t)(c * CH + 2 * i)) * 256 + 8 * lane;
        unsigned short* lp = lbase + i * 512;      // wave-uniform dest
        __builtin_amdgcn_global_load_lds((u16_g*)gp, (u16_l*)lp, 16, 0, 0);
    }
}

__device__ __forceinline__ void step5(float ex, float ey, float ez, float ew, float eqt,
                                      float m21, float m23,
                                      float& p0, float& p1, float& p2, float& p3, float& q) {
    float shp3 = shift_up1(p3);
    float n0 = (p0 + shp3) * ex;
    float n1 = fmaf(m21, shp3, p1 + p0) * ey;
    float n2 = (p2 + p1) * ez;
    float n3 = fmaf(m23, p1, p3 + p2) * ew;
    q = (q + p3) * eqt;
    p0 = n0; p1 = n1; p2 = n2; p3 = n3;
}

#define RLANE(x, j) __uint_as_float((unsigned)__builtin_amdgcn_readlane((int)__float_as_uint(x), (j)))

template <int FIRST>
__device__ __forceinline__ void compute_chunk(const unsigned short* bufp, float eqc, int lane,
                                              float m21, float m23,
                                              float& p0, float& p1, float& p2, float& p3,
                                              float& q, int& E) {
    #pragma unroll
    for (int jp = 0; jp < CH / 2; ++jp) {
        uint4 w = *(const uint4*)(bufp + jp * 512 + 8 * lane);   // ds_read_b128: 2 rows
        if (!(FIRST && jp == 0)) {   // even row (skip t=0 in first chunk)
            step5(bf16lo(w.x), bf16hi(w.x), bf16lo(w.y), bf16hi(w.y),
                  RLANE(eqc, 2 * jp), m21, m23, p0, p1, p2, p3, q);
        }
        // odd row
        step5(bf16lo(w.z), bf16hi(w.z), bf16lo(w.w), bf16hi(w.w),
              RLANE(eqc, 2 * jp + 1), m21, m23, p0, p1, p2, p3, q);
        if ((jp & 3) == 3) {   // rescale after steps 7,15,... (identical cadence)
            float mx = fmaxf(fmaxf(p0, p1), fmaxf(p2, fmaxf(p3, q)));
            mx = wave_max_nn(mx);
            int e2_ = (int)((__float_as_uint(mx) >> 23) & 0xFF) - 126;
            float sc_ = __uint_as_float((unsigned)(127 - e2_) << 23);
            p0 *= sc_; p1 *= sc_; p2 *= sc_; p3 *= sc_; q *= sc_;
            E += e2_;
        }
    }
}

// ================= Kernel B: linear CTC forward =================
// 8 waves co-issue the chunk DMA; wave 0 computes. ONLY fence: __syncthreads().
__global__ __launch_bounds__(NW * 64) void ctc_lds_kernel(const unsigned short* __restrict__ ea,
                                                          const float* __restrict__ eqg,
                                                          const int* __restrict__ labels,
                                                          const int* __restrict__ lens,
                                                          float* __restrict__ loss) {
    __shared__ unsigned short buf[2][CH * 256];   // 2 x 32 KB = 64 KB
    const int b = blockIdx.x;
    const int tid = threadIdx.x;
    const int lane = tid & 63;
    const int wid = tid >> 6;
    const int ll = lens[b];
    const unsigned short* gbase = ea + (size_t)b * T_ * 256;
    const float* qbase = eqg + b * T_;

    // skip masks (wave 0 only)
    float m21 = 0.f, m23 = 0.f;
    if (wid == 0) {
        int s1 = 4 * lane + 1;
        if (s1 >= 3) {
            int li = s1 >> 1;   // 2*lane
            m21 = (labels[b * L_ + li] != labels[b * L_ + li - 1]) ? 1.f : 0.f;
        }
        int li3 = (4 * lane + 3) >> 1;  // 2*lane+1
        m23 = (labels[b * L_ + li3] != labels[b * L_ + li3 - 1]) ? 1.f : 0.f;
    }

    // prologue: stage chunk 0
    stage_chunk_split(gbase, 0, buf[0], lane, wid);
    float eqC = 0.f, eqN = 0.f;
    if (wid == 0) eqC = qbase[lane];
    __syncthreads();

    float p0 = 0.f, p1 = 0.f, p2 = 0.f, p3 = 0.f, q = 0.f;
    if (wid == 0) {
        // row 0 = pair 0, parity 0: lane's 8B at byte offset lane*16
        ushort4 r0 = *(const ushort4*)(&buf[0][8 * lane]);
        p0 = (lane == 0) ? bf16_to_f32(r0.x) : 0.f;
        p1 = (lane == 0) ? bf16_to_f32(r0.y) : 0.f;
    }
    int E = 0;

    #pragma unroll 1
    for (int c = 0; c < NCH; ++c) {
        if (c + 1 < NCH) {
            stage_chunk_split(gbase, c + 1, buf[(c + 1) & 1], lane, wid);
            if (wid == 0) eqN = qbase[(c + 1) * CH + lane];
        }
        if (wid == 0) {
            if (c == 0) compute_chunk<1>(buf[0],     eqC, lane, m21, m23, p0, p1, p2, p3, q, E);
            else        compute_chunk<0>(buf[c & 1], eqC, lane, m21, m23, p0, p1, p2, p3, q, E);
            eqC = eqN;
        }
        __syncthreads();
    }

    // termination: reuse buf as f32 gather scratch
    float* pf = (float*)(&buf[0][0]);
    if (wid == 0) {
        *(float4*)(pf + 4 * lane) = make_float4(p0, p1, p2, p3);
        if (lane == 63) pf[256] = q;
    }
    __syncthreads();
    if (tid == 0) {
        float a1 = pf[2 * ll];
        float a2 = (ll > 0) ? pf[2 * ll - 1] : 0.f;
        loss[b] = -(__logf(a1 + a2) + ((float)E - 10240.0f) * LN2F);
    }
}

__global__ void mean_kernel(const float* __restrict__ loss, float* __restrict__ out) {
    if (threadIdx.x == 0) {
        float s = 0.f;
        for (int i = 0; i < B_; ++i) s += loss[i];
        out[0] = s / (float)B_;
    }
}

// ================= FALLBACK PATH (small ws) =================

__global__ __launch_bounds__(256) void lse_kernel(const float* __restrict__ logits,
                                                  float* __restrict__ lse) {
    const int row = blockIdx.x;
    const float* __restrict__ x = logits + (size_t)row * C_;
    const int tid = threadIdx.x, lane = tid & 63, wid = tid >> 6;
    float v0 = x[tid], v1 = x[tid + 256], v2 = x[tid + 512];
    bool h3 = (tid + 768) < C_;
    float v3 = h3 ? x[tid + 768] : NEGV;
    float m = fmaxf(fmaxf(v0, v1), fmaxf(v2, v3));
    #pragma unroll
    for (int off = 32; off > 0; off >>= 1) m = fmaxf(m, __shfl_down(m, off));
    __shared__ float wred[4]; __shared__ float bm;
    if (lane == 0) wred[wid] = m;
    __syncthreads();
    if (tid == 0) bm = fmaxf(fmaxf(wred[0], wred[1]), fmaxf(wred[2], wred[3]));
    __syncthreads();
    m = bm;
    float s = __expf(v0 - m) + __expf(v1 - m) + __expf(v2 - m);
    if (h3) s += __expf(v3 - m);
    #pragma unroll
    for (int off = 32; off > 0; off >>= 1) s += __shfl_down(s, off);
    __syncthreads();
    if (lane == 0) wred[wid] = s;
    __syncthreads();
    if (tid == 0) lse[row] = m + __logf(wred[0] + wred[1] + wred[2] + wred[3]);
}

__global__ __launch_bounds__(320) void ctc_alpha_kernel(const float* __restrict__ logits,
                                                        const int* __restrict__ labels,
                                                        const int* __restrict__ lens,
                                                        const float* __restrict__ lse,
                                                        float* __restrict__ loss) {
    const int b = blockIdx.x;
    const int s = threadIdx.x;
    const int ll = lens[b];
    __shared__ float albuf[2][S_ + 2];
    if (s < 2) { albuf[0][s] = NEGV; albuf[1][s] = NEGV; }
    int cls = BLANK; bool allow2 = false;
    if (s < S_ && (s & 1)) {
        cls = labels[b * L_ + (s >> 1)];
        allow2 = (s >= 3) && (cls != labels[b * L_ + (s >> 1) - 1]);
    }
    const bool valid = (s < 2 * ll + 1);
    const float* __restrict__ xb = logits + (size_t)b * T_ * C_;
    const float* __restrict__ lseb = lse + b * T_;
    if (s < S_) {
        float e0 = xb[cls] - lseb[0];
        float a = (s == 0 || (s == 1 && ll > 0)) ? e0 : NEGV;
        if (!valid) a = NEGV;
        albuf[0][2 + s] = a;
    }
    __syncthreads();
    float e_next = xb[(size_t)C_ + cls];
    float lse_next = lseb[1];
    int cur = 0;
    for (int t = 1; t < T_; ++t) {
        const float e = e_next, lse_t = lse_next;
        if (t + 1 < T_) { e_next = xb[(size_t)(t + 1) * C_ + cls]; lse_next = lseb[t + 1]; }
        if (s < S_) {
            float a0 = albuf[cur][2 + s];
            float a1 = albuf[cur][1 + s];
            float a2 = allow2 ? albuf[cur][s] : NEGV;
            float m = fmaxf(fmaxf(a0, a1), a2);
            float r = m + __logf(__expf(a0 - m) + __expf(a1 - m) + __expf(a2 - m)) + (e - lse_t);
            if (!valid) r = NEGV;
            albuf[cur ^ 1][2 + s] = r;
        }
        __syncthreads();
        cur ^= 1;
    }
    if (s == 0) {
        float a1 = albuf[cur][2 + 2 * ll];
        float a2 = (ll > 0) ? albuf[cur][2 + 2 * ll - 1] : NEGV;
        float m = fmaxf(a1, a2);
        loss[b] = -(m + __logf(__expf(a1 - m) + __expf(a2 - m)));
    }
}

// ================= launch =================

extern "C" void kernel_launch(void* const* d_in, const int* in_sizes, int n_in,
                              void* d_out, int out_size, void* d_ws, size_t ws_size,
                              hipStream_t stream) {
    const float* logits = (const float*)d_in[0];
    const int*   labels = (const int*)d_in[1];
    const int*   lens   = (const int*)d_in[2];
    float* out = (float*)d_out;

    const size_t ea_elems = (size_t)B_ * T_ * 256;           // ushorts
    const size_t eq_elems = (size_t)B_ * T_;                 // floats
    const size_t need = ea_elems * 2 + (eq_elems + B_) * 4;

    if (ws_size >= need) {
        unsigned short* ea = (unsigned short*)d_ws;
        float* eq   = (float*)(ea + ea_elems);
        float* loss = eq + eq_elems;
        dim3 grid(T_ / 4, B_);
        stage_kernel<<<grid, 256, 0, stream>>>(logits, labels, lens, ea, eq);
        ctc_lds_kernel<<<B_, NW * 64, 0, stream>>>(ea, eq, labels, lens, loss);
        mean_kernel<<<1, 64, 0, stream>>>(loss, out);
    } else {
        float* lse  = (float*)d_ws;
        float* loss = lse + (size_t)B_ * T_;
        lse_kernel<<<B_ * T_, 256, 0, stream>>>(logits, lse);
        ctc_alpha_kernel<<<B_, 320, 0, stream>>>(logits, labels, lens, lse, loss);
        mean_kernel<<<1, 64, 0, stream>>>(loss, out);
    }
}

// Round 15
// 73.925 us; speedup vs baseline: 1.4940x; 1.0642x over previous
//
#include <hip/hip_runtime.h>
#include <math.h>

#define B_ 32
#define T_ 1024
#define C_ 801
#define L_ 128
#define S_ 257            // 2*L+1
#define BLANK 800
#define NEGV -1e30f

#define CH 128            // chunk rows (labels-only: 256B/row -> 32KB/chunk)
#define NCH (T_ / CH)     // 8 chunks
#define NW 8              // waves per block (ctc kernel)
#define LN2F 0.69314718055994531f

typedef const unsigned __attribute__((address_space(1))) u32_g;
typedef unsigned __attribute__((address_space(3))) u32_l;

// -------- DPP helpers --------
template <int CTRL>
__device__ __forceinline__ float dppf(float v) {
    return __uint_as_float((unsigned)__builtin_amdgcn_update_dpp(
        0, (int)__float_as_uint(v), CTRL, 0xf, 0xf, true));
}
// lane l gets lane l-1's value; lane 0 gets 0.0f   [wave_shr:1]
__device__ __forceinline__ float shift_up1(float v) { return dppf<0x138>(v); }

// butterfly reduce; result valid in LANE 63 for ANY input values
__device__ __forceinline__ float wave_red_max63(float v) {
    v = fmaxf(v, dppf<0xB1>(v));    // xor1
    v = fmaxf(v, dppf<0x4E>(v));    // xor2
    v = fmaxf(v, dppf<0x141>(v));   // row_half_mirror (xor4)
    v = fmaxf(v, dppf<0x140>(v));   // row_mirror      (xor8)
    v = fmaxf(v, dppf<0x142>(v));   // row_bcast15
    v = fmaxf(v, dppf<0x143>(v));   // row_bcast31
    return v;
}
__device__ __forceinline__ float wave_red_sum63(float v) {
    v += dppf<0xB1>(v);
    v += dppf<0x4E>(v);
    v += dppf<0x141>(v);
    v += dppf<0x140>(v);
    v += dppf<0x142>(v);
    v += dppf<0x143>(v);
    return v;
}
__device__ __forceinline__ float bcast63(float v) {
    return __uint_as_float((unsigned)__builtin_amdgcn_readlane((int)__float_as_uint(v), 63));
}
__device__ __forceinline__ float wave_max_nn(float v) { return bcast63(wave_red_max63(v)); }

__device__ __forceinline__ float bf16lo(unsigned u) { return __uint_as_float(u << 16); }
__device__ __forceinline__ float bf16hi(unsigned u) { return __uint_as_float(u & 0xFFFF0000u); }
__device__ __forceinline__ unsigned short f32_to_bf16_rne(float f) {
    unsigned u = __float_as_uint(f);
    u += 0x7FFF + ((u >> 16) & 1);
    return (unsigned short)(u >> 16);
}

#define RLANE(x, j) __uint_as_float((unsigned)__builtin_amdgcn_readlane((int)__float_as_uint(x), (j)))

// ================= Kernel A: vectorized fused LSE + labels-only bf16 staging ==============
// Block = 4 rows (12816 B, float4-aligned). el[row][lane] = packed {bf16 el0, bf16 el1}
// (label emissions for states 4l+1, 4l+3; odd-state validity folded; pre-scaled 2^10).
// ebq[row] = f32 blank emission (pre-scaled).
__global__ __launch_bounds__(256) void stage_kernel(const float* __restrict__ logits,
                                                    const int* __restrict__ labels,
                                                    const int* __restrict__ lens,
                                                    unsigned* __restrict__ ea32,
                                                    float* __restrict__ ebq) {
    const int tid = threadIdx.x, lane = tid & 63, wv = tid >> 6;
    const int b = blockIdx.y;
    const int t0 = blockIdx.x * 4;
    const float* __restrict__ base = logits + ((size_t)b * T_ + t0) * C_;  // 16B-aligned
    __shared__ float xs[4 * C_];

    const float4* src = (const float4*)base;
    #pragma unroll
    for (int k = 0; k < 4; ++k) {
        int idx = tid + 256 * k;
        if (idx < 801) ((float4*)xs)[idx] = src[idx];
    }
    __syncthreads();

    const float* xr = xs + wv * C_;
    float v[13];
    float m = NEGV;
    #pragma unroll
    for (int k = 0; k < 12; ++k) { v[k] = xr[lane + 64 * k]; m = fmaxf(m, v[k]); }
    v[12] = (lane < 33) ? xr[768 + lane] : NEGV;
    m = fmaxf(m, v[12]);
    m = bcast63(wave_red_max63(m));

    float s = 0.f;
    #pragma unroll
    for (int k = 0; k < 13; ++k) s += __expf(v[k] - m);
    s = bcast63(wave_red_sum63(s));
    const float lse = m + __logf(s);

    const int ll = lens[b];
    const int row = b * T_ + (t0 + wv);
    const float ebl = __expf(xr[BLANK] - lse) * 1024.0f;
    const int cls1 = labels[b * L_ + 2 * lane];
    const int cls3 = labels[b * L_ + 2 * lane + 1];
    float e1 = (2 * lane     < ll) ? __expf(xr[cls1] - lse) * 1024.0f : 0.f;
    float e3 = (2 * lane + 1 < ll) ? __expf(xr[cls3] - lse) * 1024.0f : 0.f;

    unsigned pack = ((unsigned)f32_to_bf16_rne(e3) << 16) | (unsigned)f32_to_bf16_rne(e1);
    ea32[(size_t)row * 64 + lane] = pack;      // fully coalesced 4B/lane
    if (lane == 0) ebq[row] = ebl;
}

// ================= Kernel B helpers =================

// 128 rows/chunk, 8 waves: wave w DMAs rows {w, w+8, ...} (16 size-4 instrs each).
__device__ __forceinline__ void stage_chunk_split(const unsigned* gbase, int c,
                                                  unsigned* lbase, int lane, int wid) {
    #pragma unroll
    for (int k = 0; k < CH / NW; ++k) {
        int r = wid + k * NW;
        const unsigned* gp = gbase + ((size_t)(c * CH + r)) * 64 + lane;  // per-lane 4B
        unsigned* lp = lbase + r * 64;                                    // wave-uniform dest
        __builtin_amdgcn_global_load_lds((u32_g*)gp, (u32_l*)lp, 4, 0, 0);
    }
}

template <int FIRST>
__device__ __forceinline__ void compute_chunk(const unsigned* bufp, float ebv0, float ebv1,
                                              int lane, float m21, float m23,
                                              float mask0, float mask2, float kq,
                                              float& p0, float& p1, float& p2, float& p3,
                                              float& q, int& E) {
    #pragma unroll
    for (int g = 0; g < CH / 8; ++g) {
        // batch 8 independent ds_read_b32 before the 8 dependent steps
        unsigned u[8];
        #pragma unroll
        for (int k = 0; k < 8; ++k) u[k] = bufp[(g * 8 + k) * 64 + lane];
        #pragma unroll
        for (int k = 0; k < 8; ++k) {
            if (FIRST && g == 0 && k == 0) continue;   // t=0 handled by init
            const int j = g * 8 + k;
            float ebt = (j < 64) ? RLANE(ebv0, j) : RLANE(ebv1, j - 64);
            float el0 = bf16lo(u[k]);
            float el1 = bf16hi(u[k]);
            float ebm0 = ebt * mask0;
            float ebm2 = ebt * mask2;
            float eqm  = ebt * kq;
            float shp3 = shift_up1(p3);
            float n0 = (p0 + shp3) * ebm0;
            float n1 = fmaf(m21, shp3, p1 + p0) * el0;
            float n2 = (p2 + p1) * ebm2;
            float n3 = fmaf(m23, p1, p3 + p2) * el1;
            q = (q + p3) * eqm;
            p0 = n0; p1 = n1; p2 = n2; p3 = n3;
        }
        // rescale after steps 7,15,... (identical cadence to prior rounds)
        float mx = fmaxf(fmaxf(p0, p1), fmaxf(p2, fmaxf(p3, q)));
        mx = wave_max_nn(mx);
        int e2_ = (int)((__float_as_uint(mx) >> 23) & 0xFF) - 126;
        float sc_ = __uint_as_float((unsigned)(127 - e2_) << 23);
        p0 *= sc_; p1 *= sc_; p2 *= sc_; p3 *= sc_; q *= sc_;
        E += e2_;
    }
}

// ================= Kernel B: linear CTC forward =================
// 8 waves co-issue the chunk DMA; wave 0 computes. ONLY fence: __syncthreads().
__global__ __launch_bounds__(NW * 64) void ctc_lds_kernel(const unsigned* __restrict__ ea32,
                                                          const float* __restrict__ ebq,
                                                          const int* __restrict__ labels,
                                                          const int* __restrict__ lens,
                                                          float* __restrict__ loss) {
    __shared__ unsigned buf[2][CH * 64];   // 2 x 32 KB
    const int b = blockIdx.x;
    const int tid = threadIdx.x;
    const int lane = tid & 63;
    const int wid = tid >> 6;
    const int ll = lens[b];
    const unsigned* gbase = ea32 + (size_t)b * T_ * 64;
    const float* qb = ebq + b * T_;

    // per-lane constants (wave 0 only)
    float m21 = 0.f, m23 = 0.f, mask0 = 0.f, mask2 = 0.f, kq = 0.f;
    if (wid == 0) {
        int s1 = 4 * lane + 1;
        if (s1 >= 3) {
            int li = s1 >> 1;   // 2*lane
            m21 = (labels[b * L_ + li] != labels[b * L_ + li - 1]) ? 1.f : 0.f;
        }
        int li3 = (4 * lane + 3) >> 1;  // 2*lane+1
        m23 = (labels[b * L_ + li3] != labels[b * L_ + li3 - 1]) ? 1.f : 0.f;
        const int smax = 2 * ll + 1;
        mask0 = (4 * lane     < smax) ? 1.f : 0.f;
        mask2 = (4 * lane + 2 < smax) ? 1.f : 0.f;
        kq    = (ll == 128) ? 1.f : 0.f;
    }

    // prologue: stage chunk 0
    stage_chunk_split(gbase, 0, buf[0], lane, wid);
    float ebv0 = 0.f, ebv1 = 0.f, ebn0 = 0.f, ebn1 = 0.f;
    if (wid == 0) { ebv0 = qb[lane]; ebv1 = qb[64 + lane]; }
    __syncthreads();

    float p0 = 0.f, p1 = 0.f, p2 = 0.f, p3 = 0.f, q = 0.f;
    if (wid == 0) {
        float eb0 = RLANE(ebv0, 0);
        unsigned w0 = buf[0][lane];
        p0 = (lane == 0) ? eb0 : 0.f;          // state 0 (blank), valid
        p1 = (lane == 0) ? bf16lo(w0) : 0.f;   // state 1 (first label; validity folded)
    }
    int E = 0;

    #pragma unroll 1
    for (int c = 0; c < NCH; ++c) {
        if (c + 1 < NCH) {
            stage_chunk_split(gbase, c + 1, buf[(c + 1) & 1], lane, wid);
            if (wid == 0) { ebn0 = qb[(c + 1) * CH + lane]; ebn1 = qb[(c + 1) * CH + 64 + lane]; }
        }
        if (wid == 0) {
            if (c == 0) compute_chunk<1>(buf[0],     ebv0, ebv1, lane, m21, m23,
                                         mask0, mask2, kq, p0, p1, p2, p3, q, E);
            else        compute_chunk<0>(buf[c & 1], ebv0, ebv1, lane, m21, m23,
                                         mask0, mask2, kq, p0, p1, p2, p3, q, E);
            ebv0 = ebn0; ebv1 = ebn1;
        }
        __syncthreads();
    }

    // termination: reuse buf as f32 gather scratch
    float* pf = (float*)(&buf[0][0]);
    if (wid == 0) {
        *(float4*)(pf + 4 * lane) = make_float4(p0, p1, p2, p3);
        if (lane == 63) pf[256] = q;
    }
    __syncthreads();
    if (tid == 0) {
        float a1 = pf[2 * ll];
        float a2 = (ll > 0) ? pf[2 * ll - 1] : 0.f;
        loss[b] = -(__logf(a1 + a2) + ((float)E - 10240.0f) * LN2F);
    }
}

__global__ void mean_kernel(const float* __restrict__ loss, float* __restrict__ out) {
    if (threadIdx.x == 0) {
        float s = 0.f;
        for (int i = 0; i < B_; ++i) s += loss[i];
        out[0] = s / (float)B_;
    }
}

// ================= FALLBACK PATH (small ws) =================

__global__ __launch_bounds__(256) void lse_kernel(const float* __restrict__ logits,
                                                  float* __restrict__ lse) {
    const int row = blockIdx.x;
    const float* __restrict__ x = logits + (size_t)row * C_;
    const int tid = threadIdx.x, lane = tid & 63, wid = tid >> 6;
    float v0 = x[tid], v1 = x[tid + 256], v2 = x[tid + 512];
    bool h3 = (tid + 768) < C_;
    float v3 = h3 ? x[tid + 768] : NEGV;
    float m = fmaxf(fmaxf(v0, v1), fmaxf(v2, v3));
    #pragma unroll
    for (int off = 32; off > 0; off >>= 1) m = fmaxf(m, __shfl_down(m, off));
    __shared__ float wred[4]; __shared__ float bm;
    if (lane == 0) wred[wid] = m;
    __syncthreads();
    if (tid == 0) bm = fmaxf(fmaxf(wred[0], wred[1]), fmaxf(wred[2], wred[3]));
    __syncthreads();
    m = bm;
    float s = __expf(v0 - m) + __expf(v1 - m) + __expf(v2 - m);
    if (h3) s += __expf(v3 - m);
    #pragma unroll
    for (int off = 32; off > 0; off >>= 1) s += __shfl_down(s, off);
    __syncthreads();
    if (lane == 0) wred[wid] = s;
    __syncthreads();
    if (tid == 0) lse[row] = m + __logf(wred[0] + wred[1] + wred[2] + wred[3]);
}

__global__ __launch_bounds__(320) void ctc_alpha_kernel(const float* __restrict__ logits,
                                                        const int* __restrict__ labels,
                                                        const int* __restrict__ lens,
                                                        const float* __restrict__ lse,
                                                        float* __restrict__ loss) {
    const int b = blockIdx.x;
    const int s = threadIdx.x;
    const int ll = lens[b];
    __shared__ float albuf[2][S_ + 2];
    if (s < 2) { albuf[0][s] = NEGV; albuf[1][s] = NEGV; }
    int cls = BLANK; bool allow2 = false;
    if (s < S_ && (s & 1)) {
        cls = labels[b * L_ + (s >> 1)];
        allow2 = (s >= 3) && (cls != labels[b * L_ + (s >> 1) - 1]);
    }
    const bool valid = (s < 2 * ll + 1);
    const float* __restrict__ xb = logits + (size_t)b * T_ * C_;
    const float* __restrict__ lseb = lse + b * T_;
    if (s < S_) {
        float e0 = xb[cls] - lseb[0];
        float a = (s == 0 || (s == 1 && ll > 0)) ? e0 : NEGV;
        if (!valid) a = NEGV;
        albuf[0][2 + s] = a;
    }
    __syncthreads();
    float e_next = xb[(size_t)C_ + cls];
    float lse_next = lseb[1];
    int cur = 0;
    for (int t = 1; t < T_; ++t) {
        const float e = e_next, lse_t = lse_next;
        if (t + 1 < T_) { e_next = xb[(size_t)(t + 1) * C_ + cls]; lse_next = lseb[t + 1]; }
        if (s < S_) {
            float a0 = albuf[cur][2 + s];
            float a1 = albuf[cur][1 + s];
            float a2 = allow2 ? albuf[cur][s] : NEGV;
            float m = fmaxf(fmaxf(a0, a1), a2);
            float r = m + __logf(__expf(a0 - m) + __expf(a1 - m) + __expf(a2 - m)) + (e - lse_t);
            if (!valid) r = NEGV;
            albuf[cur ^ 1][2 + s] = r;
        }
        __syncthreads();
        cur ^= 1;
    }
    if (s == 0) {
        float a1 = albuf[cur][2 + 2 * ll];
        float a2 = (ll > 0) ? albuf[cur][2 + 2 * ll - 1] : NEGV;
        float m = fmaxf(a1, a2);
        loss[b] = -(m + __logf(__expf(a1 - m) + __expf(a2 - m)));
    }
}

// ================= launch =================

extern "C" void kernel_launch(void* const* d_in, const int* in_sizes, int n_in,
                              void* d_out, int out_size, void* d_ws, size_t ws_size,
                              hipStream_t stream) {
    const float* logits = (const float*)d_in[0];
    const int*   labels = (const int*)d_in[1];
    const int*   lens   = (const int*)d_in[2];
    float* out = (float*)d_out;

    const size_t ea_elems = (size_t)B_ * T_ * 64;            // uints (packed bf16 pairs)
    const size_t eb_elems = (size_t)B_ * T_;                 // floats
    const size_t need = (ea_elems + eb_elems + B_) * 4;

    if (ws_size >= need) {
        unsigned* ea32 = (unsigned*)d_ws;
        float* ebq  = (float*)(ea32 + ea_elems);
        float* loss = ebq + eb_elems;
        dim3 grid(T_ / 4, B_);
        stage_kernel<<<grid, 256, 0, stream>>>(logits, labels, lens, ea32, ebq);
        ctc_lds_kernel<<<B_, NW * 64, 0, stream>>>(ea32, ebq, labels, lens, loss);
        mean_kernel<<<1, 64, 0, stream>>>(loss, out);
    } else {
        float* lse  = (float*)d_ws;
        float* loss = lse + (size_t)B_ * T_;
        lse_kernel<<<B_ * T_, 256, 0, stream>>>(logits, lse);
        ctc_alpha_kernel<<<B_, 320, 0, stream>>>(logits, labels, lens, lse, loss);
        mean_kernel<<<1, 64, 0, stream>>>(loss, out);
    }
}